// Round 14
// baseline (318.117 us; speedup 1.0000x reference)
//
#include <hip/hip_runtime.h>

#define B 64
#define T 4096
#define AD 1024   // ATTN_RNN_DIM
#define HD 256    // HYPERNET_DIM
#define CH 32
#define KS 31
#define OD 128
#define PADW 15
#define TILE_T 128
#define NCONV 2048          // B * T/TILE_T
#define GRID 768            // 3 blocks/CU exactly -> co-residency guaranteed

// LDS-only barrier: orders ds_write->ds_read without draining global stores
#define LDS_BARRIER() asm volatile("s_waitcnt lgkmcnt(0)\n\ts_barrier" ::: "memory")

union SmemU {
    float qs[AD];                                               // phase H: 4 KB
    struct { float hs[HD]; float cwl[CH*2]; float wfs_t[CH*OD]; } cg;  // 17.3 KB
    struct { float tileo[64][128]; float pa[192]; } cv;         // 33.5 KB
};

// sense-reversing grid barrier, device-scope atomics in d_ws.
// gen is read BEFORE the arrive-add, so a releasing bump (which requires our
// add) can never be observed before our own arrival -> no lost-wakeup race.
__device__ __forceinline__ void grid_barrier(unsigned* cnt, unsigned* gen) {
    __syncthreads();
    if (threadIdx.x == 0) {
        __threadfence();    // prior global writes visible device-wide
        unsigned g = __hip_atomic_load(gen, __ATOMIC_RELAXED, __HIP_MEMORY_SCOPE_AGENT);
        unsigned a = __hip_atomic_fetch_add(cnt, 1u, __ATOMIC_ACQ_REL, __HIP_MEMORY_SCOPE_AGENT);
        if (a == GRID - 1u) {
            __hip_atomic_store(cnt, 0u, __ATOMIC_RELAXED, __HIP_MEMORY_SCOPE_AGENT);
            __hip_atomic_store(gen, g + 1u, __ATOMIC_RELEASE, __HIP_MEMORY_SCOPE_AGENT);
        } else {
            while (__hip_atomic_load(gen, __ATOMIC_ACQUIRE, __HIP_MEMORY_SCOPE_AGENT) == g)
                __builtin_amdgcn_s_sleep(8);
        }
        __threadfence();
    }
    __syncthreads();
}

__global__ __launch_bounds__(256, 3) void k_fused(
        const float* __restrict__ q,    const float* __restrict__ prev,
        const float* __restrict__ W1,   const float* __restrict__ b1,
        const float* __restrict__ W2,   const float* __restrict__ b2,
        const float* __restrict__ Wfc,  const float* __restrict__ bfc,
        float* __restrict__ h, float* __restrict__ Gt,
        unsigned* __restrict__ bcnt, unsigned* __restrict__ bgen,
        float* __restrict__ out) {
    int bid = blockIdx.x, tid = threadIdx.x;
    int lane = tid & 63, w = tid >> 6;
    __shared__ SmemU S;

    // ---------- Phase H: h[b,j] = tanh(q[b]·W1[j] + b1[j]); unit = (b, 16-j group)
    for (int u = bid; u < 1024; u += GRID) {
        __syncthreads();                       // qs reuse across units
        int b = u >> 4, jb = (u & 15) * 16;
        #pragma unroll
        for (int p = 0; p < 4; ++p)
            S.qs[p * 256 + tid] = q[(size_t)b * AD + p * 256 + tid];
        __syncthreads();
        const float4* qs4 = (const float4*)S.qs;
        #pragma unroll
        for (int r = 0; r < 4; ++r) {
            int j = jb + w * 4 + r;
            const float4* wr = (const float4*)(W1 + (size_t)j * AD);
            float s = 0.f;
            #pragma unroll
            for (int m = 0; m < 4; ++m) {
                float4 wv = wr[m * 64 + lane];
                float4 qv = qs4[m * 64 + lane];
                s += wv.x*qv.x + wv.y*qv.y + wv.z*qv.z + wv.w*qv.w;
            }
            #pragma unroll
            for (int off = 32; off > 0; off >>= 1)
                s += __shfl_down(s, off, 64);
            if (lane == 0) h[(size_t)b * HD + j] = tanhf(s + b1[j]);
        }
    }
    grid_barrier(bcnt, bgen);

    // ---------- Phase CG: unit = (b, k-pair); cw rows wave-cooperative, then G
    #pragma unroll
    for (int p = 0; p < 16; ++p) {             // Wfc^T staged once per block
        int idx = p * 256 + tid;
        int o = idx >> 5, c = idx & 31;
        S.cg.wfs_t[c * OD + o] = Wfc[idx];
    }
    for (int u = bid; u < 1024; u += GRID) {
        __syncthreads();                       // hs/cwl reuse + wfs_t publish
        int b = u >> 4, kb = (u & 15) * 2;
        S.cg.hs[tid] = h[(size_t)b * HD + tid];
        __syncthreads();
        const float4* hs4 = (const float4*)S.cg.hs;
        float4 hv = hs4[lane];
        #pragma unroll
        for (int i = 0; i < 16; ++i) {         // 64 rows = 32c x 2k
            int n = w * 16 + i;
            int c = n >> 1, kl = n & 1;
            int kg = kb + kl;
            if (kg < KS) {
                int rr = c * KS + kg;
                float4 wv = ((const float4*)(W2 + (size_t)rr * HD))[lane];
                float s = wv.x*hv.x + wv.y*hv.y + wv.z*hv.z + wv.w*hv.w;
                #pragma unroll
                for (int off = 32; off > 0; off >>= 1)
                    s += __shfl_xor(s, off, 64);
                if (lane == 0) S.cg.cwl[c * 2 + kl] = s + b2[rr];
            }
        }
        __syncthreads();
        {
            int kl = tid >> 7, o = tid & 127;
            int kg = kb + kl;
            if (kg < KS) {
                float s = 0.f;
                #pragma unroll
                for (int c = 0; c < CH; ++c)
                    s += S.cg.wfs_t[c * OD + o] * S.cg.cwl[c * 2 + kl];
                Gt[(size_t)b * (KS * OD) + kg * OD + o] = s;
            }
        }
    }
    grid_barrier(bcnt, bgen);

    // ---------- Phase CONV: unit = tile; R11 body; 768%8==0 keeps XCD swizzle
    for (int l = bid; l < NCONV; l += GRID) {
        LDS_BARRIER();                         // pa/tileo reuse across units
        int sid  = (l & 7) * 256 + (l >> 3);
        int b    = sid >> 5;
        int tile = sid & 31;
        int t0   = tile * TILE_T;
        if (tid < TILE_T + 30) {
            int gg = t0 + tid - PADW;
            S.cv.pa[tid] = (gg >= 0 && gg < T) ? prev[(size_t)b * T + gg] : 0.f;
        }
        int o = tid & 127, half = tid >> 7;
        float g[KS];
        #pragma unroll
        for (int k = 0; k < KS; ++k)
            g[k] = Gt[(size_t)b * (KS * OD) + k * OD + o];   // coalesced, hot
        float base = bfc[o];
        LDS_BARRIER();

        #pragma unroll
        for (int pass = 0; pass < 2; ++pass) {
            const float* pap = S.cv.pa + pass * 64;          // 16B-aligned
            size_t obase = ((size_t)b * T + t0 + pass * 64) * OD;
            #pragma unroll
            for (int c = 0; c < 4; ++c) {
                int s0 = half * 32 + c * 8;
                float pw[40];
                const float4* lp = (const float4*)(pap + s0);
                #pragma unroll
                for (int q4 = 0; q4 < 10; ++q4) {
                    float4 v = lp[q4];
                    pw[q4*4+0]=v.x; pw[q4*4+1]=v.y; pw[q4*4+2]=v.z; pw[q4*4+3]=v.w;
                }
                float acc[8];
                #pragma unroll
                for (int tt = 0; tt < 8; ++tt) {
                    float a = base;
                    #pragma unroll
                    for (int k = 0; k < KS; ++k)
                        a += g[k] * pw[tt + k];
                    acc[tt] = a;
                }
                #pragma unroll
                for (int tt = 0; tt < 8; ++tt)
                    S.cv.tileo[s0 + tt][o] = acc[tt];        // 2-way alias: free
                LDS_BARRIER();                 // LDS-only; stores keep flying
                #pragma unroll
                for (int j = 0; j < 2; ++j) {
                    int f  = j * 256 + tid;
                    int rl = f >> 5, c4 = f & 31;
                    int row = (j == 0) ? (c * 8 + rl) : (32 + c * 8 + (rl - 8));
                    float4 v = *(const float4*)&S.cv.tileo[row][c4 * 4];
                    *(float4*)(out + obase + (size_t)row * OD + c4 * 4) = v;
                }
            }
        }
    }
}

extern "C" void kernel_launch(void* const* d_in, const int* in_sizes, int n_in,
                              void* d_out, int out_size, void* d_ws, size_t ws_size,
                              hipStream_t stream) {
    const float* query = (const float*)d_in[0];
    const float* prev  = (const float*)d_in[1];
    const float* W1    = (const float*)d_in[2];
    const float* b1    = (const float*)d_in[3];
    const float* W2    = (const float*)d_in[4];
    const float* b2    = (const float*)d_in[5];
    const float* Wfc   = (const float*)d_in[6];
    const float* bfc   = (const float*)d_in[7];
    float* out = (float*)d_out;

    float* h  = (float*)d_ws;                       // 16384 floats
    float* Gt = h + B * HD;                         // 253952 floats
    unsigned* bcnt = (unsigned*)((char*)d_ws + 1081344);  // 128B-aligned
    unsigned* bgen = bcnt + 32;                     // separate cache line

    // zero barrier state every launch (graph-capturable, replay-consistent)
    hipMemsetAsync((void*)bcnt, 0, 256, stream);

    k_fused<<<dim3(GRID), dim3(256), 0, stream>>>(
        query, prev, W1, b1, W2, b2, Wfc, bfc, h, Gt, bcnt, bgen, out);
}

// Round 15
// 51.969 us; speedup vs baseline: 6.1212x; 6.1212x over previous
//
#include <hip/hip_runtime.h>

#define B 64
#define T 4096
#define AD 1024   // ATTN_RNN_DIM
#define HD 256    // HYPERNET_DIM
#define CH 32
#define KS 31
#define OD 128
#define PADW 15
#define CWN (CH*KS)   // 992
#define TILE_T 128
#define NTILE (T / TILE_T)   // 32

// LDS-only barrier: orders ds_write->ds_read without draining global stores
#define LDS_BARRIER() asm volatile("s_waitcnt lgkmcnt(0)\n\ts_barrier" ::: "memory")

// ---------------- Kernel A: h[b,j] = tanh(dot(query[b,:], W1[j,:]) + b1[j])
// 1024 blocks: block = (b, 16-j group); q[b] staged once in LDS; 4 j per wave
__global__ __launch_bounds__(256) void k_hyper1(const float* __restrict__ q,
        const float* __restrict__ W1, const float* __restrict__ b1,
        float* __restrict__ h) {
    int bid  = blockIdx.x;            // 0..1023
    int tid  = threadIdx.x;
    int lane = tid & 63, w = tid >> 6;
    int b  = bid >> 4;                // 16 blocks per b
    int jb = (bid & 15) * 16;         // this block's 16 j's
    __shared__ float qs[AD];          // 4 KB
    #pragma unroll
    for (int p = 0; p < 4; ++p)
        qs[p * 256 + tid] = q[(size_t)b * AD + p * 256 + tid];
    __syncthreads();
    const float4* qs4 = (const float4*)qs;
    #pragma unroll
    for (int r = 0; r < 4; ++r) {
        int j = jb + w * 4 + r;
        const float4* wr = (const float4*)(W1 + (size_t)j * AD);
        float s = 0.f;
        #pragma unroll
        for (int m = 0; m < 4; ++m) {
            float4 wv = wr[m * 64 + lane];
            float4 qv = qs4[m * 64 + lane];
            s += wv.x*qv.x + wv.y*qv.y + wv.z*qv.z + wv.w*qv.w;
        }
        #pragma unroll
        for (int off = 32; off > 0; off >>= 1)
            s += __shfl_down(s, off, 64);
        if (lane == 0) h[(size_t)b * HD + j] = tanhf(s + b1[j]);
    }
}

// ---------------- Kernel B (fused cw+G): block (b,q) owns k in [8q, min(8q+8,31))
__global__ __launch_bounds__(256) void k_cwG(const float* __restrict__ h,
        const float* __restrict__ W2, const float* __restrict__ b2,
        const float* __restrict__ Wfc, float* __restrict__ Gt) {
    int b = blockIdx.x >> 2;
    int q = blockIdx.x & 3;
    int tid = threadIdx.x;
    __shared__ float hs[HD];           // 1 KB
    __shared__ float cwl[CH * 8];      // [c][kk], 1 KB
    __shared__ float wfs_t[CH * OD];   // [c][o], 16 KB
    hs[tid] = h[(size_t)b * HD + tid];
    #pragma unroll
    for (int p = 0; p < 16; ++p) {
        int idx = p * 256 + tid;
        int o = idx >> 5, c = idx & 31;
        wfs_t[c * OD + o] = Wfc[idx];
    }
    __syncthreads();
    {
        int c = tid >> 3, kk = tid & 7;
        int k = q * 8 + kk;
        if (k < KS) {
            int r = c * KS + k;
            const float4* wr  = (const float4*)(W2 + (size_t)r * HD);
            const float4* hs4 = (const float4*)hs;
            float s = 0.f;
            #pragma unroll
            for (int m = 0; m < HD / 4; ++m) {
                float4 w = wr[m], hv = hs4[m];
                s += w.x * hv.x + w.y * hv.y + w.z * hv.z + w.w * hv.w;
            }
            cwl[c * 8 + kk] = s + b2[r];
        }
    }
    __syncthreads();
    #pragma unroll
    for (int p = 0; p < 4; ++p) {
        int idx = p * 256 + tid;
        int kl = idx >> 7, o = idx & 127;
        int kg = q * 8 + kl;
        if (kg < KS) {
            float s = 0.f;
            #pragma unroll
            for (int c = 0; c < CH; ++c)
                s += wfs_t[c * OD + o] * cwl[c * 8 + kl];   // bcast + stride-1
            Gt[(size_t)b * (KS * OD) + kg * OD + o] = s;
        }
    }
}

// ---------------- Kernel C: out[b,t,o] = sum_k Gt[b,k,o]*pa[b,t+k-15] + bfc[o]
__device__ __forceinline__ void compute_chunk(const float* pa, int s0, float base,
                                              const float (&g)[KS], float (&acc)[8]) {
    float pw[40];
    const float4* lp = (const float4*)(pa + s0);   // s0 % 8 == 0 -> aligned
    #pragma unroll
    for (int q4 = 0; q4 < 10; ++q4) {
        float4 v = lp[q4];
        pw[q4*4+0] = v.x; pw[q4*4+1] = v.y; pw[q4*4+2] = v.z; pw[q4*4+3] = v.w;
    }
    #pragma unroll
    for (int tt = 0; tt < 8; ++tt) {
        float a = base;
        #pragma unroll
        for (int k = 0; k < KS; ++k)
            a += g[k] * pw[tt + k];
        acc[tt] = a;
    }
}

__global__ __launch_bounds__(256, 4) void k_conv(const float* __restrict__ pa_g,
        const float* __restrict__ Gt, const float* __restrict__ bfc,
        float* __restrict__ out) {
    int bid  = blockIdx.x;
    int sid  = (bid & 7) * 256 + (bid >> 3);
    int b    = sid >> 5;          // 32 tiles per b
    int tile = sid & 31;
    int t0   = tile * TILE_T;
    int tid  = threadIdx.x;
    __shared__ float tileo[64][128];      // 32 KB
    __shared__ float pa[TILE_T + 32];     // 158 used

    if (tid < TILE_T + 30) {
        int gg = t0 + tid - PADW;
        pa[tid] = (gg >= 0 && gg < T) ? pa_g[(size_t)b * T + gg] : 0.f;
    }
    int o = tid & 127, half = tid >> 7;
    float g[KS];
    #pragma unroll
    for (int k = 0; k < KS; ++k)
        g[k] = Gt[(size_t)b * (KS * OD) + k * OD + o];   // coalesced, L2-hot
    float base = bfc[o];
    __syncthreads();

    #pragma unroll
    for (int pass = 0; pass < 2; ++pass) {
        const float* pap = pa + pass * 64;               // keeps 16B alignment
        size_t obase = ((size_t)b * T + t0 + pass * 64) * OD;
        #pragma unroll
        for (int c = 0; c < 4; ++c) {
            int s0 = half * 32 + c * 8;
            float acc[8];
            compute_chunk(pap, s0, base, g, acc);
            #pragma unroll
            for (int tt = 0; tt < 8; ++tt)
                tileo[s0 + tt][o] = acc[tt];             // 2-way alias: free
            LDS_BARRIER();
            #pragma unroll
            for (int j = 0; j < 2; ++j) {
                int f  = j * 256 + tid;
                int rl = f >> 5, c4 = f & 31;
                int row = (j == 0) ? (c * 8 + rl) : (32 + c * 8 + (rl - 8));
                float4 v = *(const float4*)&tileo[row][c4 * 4];
                *(float4*)(out + obase + (size_t)row * OD + c4 * 4) = v;
            }
        }
    }
}

extern "C" void kernel_launch(void* const* d_in, const int* in_sizes, int n_in,
                              void* d_out, int out_size, void* d_ws, size_t ws_size,
                              hipStream_t stream) {
    const float* query = (const float*)d_in[0];
    const float* prev  = (const float*)d_in[1];
    const float* W1    = (const float*)d_in[2];
    const float* b1    = (const float*)d_in[3];
    const float* W2    = (const float*)d_in[4];
    const float* b2    = (const float*)d_in[5];
    const float* Wfc   = (const float*)d_in[6];
    const float* bfc   = (const float*)d_in[7];
    float* out = (float*)d_out;

    float* h  = (float*)d_ws;          // 16384 floats
    float* Gt = h + B * HD;            // 253952 floats

    k_hyper1<<<dim3(B * 16), dim3(256), 0, stream>>>(query, W1, b1, h);
    k_cwG   <<<dim3(B * 4), dim3(256), 0, stream>>>(h, W2, b2, Wfc, Gt);
    k_conv  <<<dim3(B * NTILE), dim3(256), 0, stream>>>(prev, Gt, bfc, out);
}